// Round 5
// baseline (398.211 us; speedup 1.0000x reference)
//
#include <hip/hip_runtime.h>
#include <hip/hip_bf16.h>

typedef unsigned short ushort_t;
typedef unsigned int u32;
typedef unsigned long long u64;
typedef _Float16 f16;
typedef __attribute__((ext_vector_type(8))) _Float16 v8h;
typedef __attribute__((ext_vector_type(4))) float v4f;

#define M_TOK 16384        // 8 * 2048 tokens
#define DDIM 512
#define NCODES 8192
#define PCODES 64          // codes per panel (LDS-resident)
#define NPANEL 128         // NCODES / PCODES
#define TCHUNK 512         // tokens per block
#define WTOK 128           // tokens per wave

// workspace layout (bytes)
#define OFF_AH   0u            // 16 MB  f16(x)
#define OFF_BH   16777216u     //  8 MB  f16(cb)
#define OFF_PART 25165824u     // 16 MB  u64 per (token, panel)
#define OFF_IDX  41943040u     // 64 KB
#define OFF_C2   42008576u     // 32 KB
#define OFF_ACC  42041344u     //  4 B

// ---------------- c2[k] = ||codebook[k]||^2 ----------------
__global__ void c2_kernel(const float* __restrict__ cb, float* __restrict__ c2) {
    int row  = blockIdx.x * 4 + (threadIdx.x >> 6);
    int lane = threadIdx.x & 63;
    const float* p = cb + (size_t)row * DDIM;
    float s = 0.f;
    #pragma unroll
    for (int d = 0; d < DDIM; d += 64) {
        float v = p[d + lane];
        s += v * v;
    }
    #pragma unroll
    for (int off = 32; off; off >>= 1) s += __shfl_down(s, off);
    if (lane == 0) c2[row] = s;
}

__global__ void zero_kernel(float* __restrict__ acc) {
    if (threadIdx.x == 0 && blockIdx.x == 0) *acc = 0.f;
}

// ---------------- fp32 -> f16, 8 elems/thread ----------------
__global__ void split_hi_kernel(const float* __restrict__ src, ushort_t* __restrict__ hi, int n8) {
    int i = blockIdx.x * blockDim.x + threadIdx.x;
    if (i >= n8) return;
    const float4* s4 = (const float4*)src + (size_t)i * 2;
    float4 a = s4[0], b = s4[1];
    float v[8] = {a.x, a.y, a.z, a.w, b.x, b.y, b.z, b.w};
    union { ushort_t u[8]; uint4 q; } H;
    #pragma unroll
    for (int j = 0; j < 8; ++j) {
        f16 h = (f16)v[j];
        __builtin_memcpy(&H.u[j], &h, 2);
    }
    *(uint4*)(hi + (size_t)i * 8) = H.q;
}

// ---------------- barrier-free panel GEMM, per-wave top-1 -----------------
// Block: 64-code B-panel resident in LDS (swizzled); 4 waves x 128 tokens.
// score = c2[n] - 2 * x.c ; per-wave 64-col winner -> part (packed u64).
__launch_bounds__(256, 2)
__global__ void gemm_panel_kernel(const ushort_t* __restrict__ Ah, const ushort_t* __restrict__ Bh,
                                  const float* __restrict__ c2, u64* __restrict__ part) {
    __shared__ __align__(16) ushort_t Bsb[PCODES * DDIM];   // 64 KB

    const int tid = threadIdx.x;
    const int wv  = tid >> 6;
    const int l   = tid & 63;
    const int lg  = l >> 4;          // 0..3
    const int lc  = l & 15;

    const int panel = blockIdx.x & (NPANEL - 1);
    const int chunk = blockIdx.x >> 7;
    const int col0  = panel * PCODES;
    const int row0  = chunk * TCHUNK + wv * WTOK;

    // ---- stage B panel once: linear LDS dest, pre-swizzled global source ----
    // LDS slot q of row r holds global k-slot (q ^ (r&7)); 16B slots.
    #pragma unroll
    for (int r = 0; r < 16; ++r) {
        int row = r * 4 + wv;
        const ushort_t* g = Bh + (size_t)(col0 + row) * DDIM + ((l ^ (row & 7)) * 8);
        __builtin_amdgcn_global_load_lds(
            (const __attribute__((address_space(1))) void*)g,
            (__attribute__((address_space(3))) void*)&Bsb[row * DDIM], 16, 0, 0);
    }
    __syncthreads();   // only barrier in the kernel; LDS read-only afterwards

    v4f acc[8][4];
    #pragma unroll
    for (int m = 0; m < 8; ++m)
        #pragma unroll
        for (int n = 0; n < 4; ++n) acc[m][n] = (v4f){0.f, 0.f, 0.f, 0.f};

    const ushort_t* abase = Ah + (size_t)(row0 + lc) * DDIM + lg * 8;

    #pragma unroll 2
    for (int ks = 0; ks < 16; ++ks) {
        const int k0 = ks * 32;
        v8h af[8], bf[4];
        #pragma unroll
        for (int m = 0; m < 8; ++m)
            af[m] = *(const v8h*)(abase + (size_t)m * 16 * DDIM + k0);
        #pragma unroll
        for (int n = 0; n < 4; ++n) {
            int row = n * 16 + lc;
            int s = (k0 >> 3) + lg;                        // k-slot 0..63
            bf[n] = *(const v8h*)&Bsb[row * DDIM + ((s ^ (row & 7)) * 8)];
        }
        #pragma unroll
        for (int m = 0; m < 8; ++m)
            #pragma unroll
            for (int n = 0; n < 4; ++n)
                acc[m][n] = __builtin_amdgcn_mfma_f32_16x16x32_f16(af[m], bf[n], acc[m][n], 0, 0, 0);
    }

    // ---- per-wave epilogue: min over 64 cols per row, write part directly ----
    // D layout: col = lc, row = lg*4 + j (HW-verified rounds 3/4)
    float c2v[4];
    #pragma unroll
    for (int n = 0; n < 4; ++n) c2v[n] = c2[col0 + n * 16 + lc];

    #pragma unroll
    for (int m = 0; m < 8; ++m) {
        #pragma unroll
        for (int j = 0; j < 4; ++j) {
            u64 best = ~0ull;
            #pragma unroll
            for (int n = 0; n < 4; ++n) {
                float sc = c2v[n] - 2.0f * acc[m][n][j];
                u32 b = __float_as_uint(sc);
                b = (b & 0x80000000u) ? ~b : (b | 0x80000000u);   // monotone float->u32
                u64 key = ((u64)b << 32) | (u32)(col0 + n * 16 + lc);
                best = key < best ? key : best;
            }
            #pragma unroll
            for (int off = 1; off < 16; off <<= 1) {
                u64 o = __shfl_xor(best, off);
                best = o < best ? o : best;
            }
            if (lc == 0) {
                int row = row0 + m * 16 + lg * 4 + j;
                part[(size_t)row * NPANEL + panel] = best;
            }
        }
    }
}

// ---------------- merge 128 partials/token -> top-4 + exact fp64 recheck ---
__global__ void reduce_recheck_kernel(const u64* __restrict__ part,
                                      const float* __restrict__ x, const float* __restrict__ cb,
                                      int* __restrict__ idx) {
    int t = blockIdx.x * 4 + (threadIdx.x >> 6);
    int l = threadIdx.x & 63;
    u64 k1 = part[(size_t)t * NPANEL + l];
    u64 k2 = part[(size_t)t * NPANEL + 64 + l];

    int cand[4];
    #pragma unroll
    for (int c = 0; c < 4; ++c) {
        u64 mm = k1 < k2 ? k1 : k2;
        #pragma unroll
        for (int off = 1; off < 64; off <<= 1) {
            u64 o = __shfl_xor(mm, off);
            mm = o < mm ? o : mm;
        }
        cand[c] = (int)(u32)(mm & 0xffffffffull);
        if (k1 == mm) k1 = ~0ull;      // keys unique (distinct cols)
        if (k2 == mm) k2 = ~0ull;
    }

    const float* xp = x + (size_t)t * DDIM + l * 8;
    float xv[8];
    #pragma unroll
    for (int j = 0; j < 8; ++j) xv[j] = xp[j];

    double d[4];
    #pragma unroll
    for (int c = 0; c < 4; ++c) {
        const float* cp = cb + (size_t)cand[c] * DDIM + l * 8;
        double s = 0.0;
        #pragma unroll
        for (int j = 0; j < 8; ++j) {
            double a = (double)cp[j] - (double)xv[j];
            s += a * a;
        }
        d[c] = s;
    }
    #pragma unroll
    for (int c = 0; c < 4; ++c) {
        #pragma unroll
        for (int off = 1; off < 64; off <<= 1) d[c] += __shfl_xor(d[c], off);
    }

    double bd = d[0]; int bi = cand[0];
    #pragma unroll
    for (int c = 1; c < 4; ++c)
        if (d[c] < bd || (d[c] == bd && cand[c] < bi)) { bd = d[c]; bi = cand[c]; }
    if (l == 0) idx[t] = bi;
}

// ---------------- gather codes, straight-through output, loss -------------
__global__ void quantize_kernel(const float* __restrict__ x, const float* __restrict__ cb,
                                const int* __restrict__ idx, float* __restrict__ out,
                                float* __restrict__ acc) {
    __shared__ float red[4];
    float local = 0.f;
    const size_t total = (size_t)M_TOK * DDIM;
    for (size_t e = (size_t)blockIdx.x * blockDim.x + threadIdx.x; e < total;
         e += (size_t)gridDim.x * blockDim.x) {
        size_t t = e >> 9;
        int d = (int)(e & 511);
        int k = idx[t];
        float c  = cb[(size_t)k * DDIM + d];
        float xv = x[e];
        float diff = c - xv;
        out[e] = xv + diff;
        local += diff * diff;
    }
    #pragma unroll
    for (int off = 32; off; off >>= 1) local += __shfl_down(local, off);
    int lane = threadIdx.x & 63, wv = threadIdx.x >> 6;
    if (lane == 0) red[wv] = local;
    __syncthreads();
    if (threadIdx.x == 0) atomicAdd(acc, red[0] + red[1] + red[2] + red[3]);
}

__global__ void finalize_kernel(const int* __restrict__ idx, const float* __restrict__ acc,
                                float* __restrict__ out) {
    int t = blockIdx.x * blockDim.x + threadIdx.x;
    if (t < M_TOK) out[(size_t)M_TOK * DDIM + t] = (float)idx[t];
    if (t == 0) {
        float mean = (*acc) / (float)((size_t)M_TOK * DDIM);
        out[(size_t)M_TOK * DDIM + M_TOK] = 2.0f * mean;
    }
}

extern "C" void kernel_launch(void* const* d_in, const int* in_sizes, int n_in,
                              void* d_out, int out_size, void* d_ws, size_t ws_size,
                              hipStream_t stream) {
    const float* x  = (const float*)d_in[0];
    const float* cb = (const float*)d_in[1];
    float* out = (float*)d_out;
    char* ws = (char*)d_ws;

    ushort_t* Ah   = (ushort_t*)(ws + OFF_AH);
    ushort_t* Bh   = (ushort_t*)(ws + OFF_BH);
    u64*      part = (u64*)(ws + OFF_PART);
    int*      idx  = (int*)(ws + OFF_IDX);
    float*    c2   = (float*)(ws + OFF_C2);
    float*    acc  = (float*)(ws + OFF_ACC);

    zero_kernel<<<1, 64, 0, stream>>>(acc);
    c2_kernel<<<NCODES / 4, 256, 0, stream>>>(cb, c2);
    split_hi_kernel<<<(M_TOK * DDIM / 8) / 256, 256, 0, stream>>>(x, Ah, M_TOK * DDIM / 8);
    split_hi_kernel<<<(NCODES * DDIM / 8) / 256, 256, 0, stream>>>(cb, Bh, NCODES * DDIM / 8);
    gemm_panel_kernel<<<(M_TOK / TCHUNK) * NPANEL, 256, 0, stream>>>(Ah, Bh, c2, part);
    reduce_recheck_kernel<<<M_TOK / 4, 256, 0, stream>>>(part, x, cb, idx);
    quantize_kernel<<<2048, 256, 0, stream>>>(x, cb, idx, out, acc);
    finalize_kernel<<<(M_TOK + 255) / 256, 256, 0, stream>>>(idx, acc, out);
}

// Round 6
// 284.634 us; speedup vs baseline: 1.3990x; 1.3990x over previous
//
#include <hip/hip_runtime.h>
#include <hip/hip_bf16.h>

typedef unsigned short ushort_t;
typedef unsigned int u32;
typedef unsigned long long u64;
typedef _Float16 f16;
typedef __attribute__((ext_vector_type(8))) _Float16 v8h;
typedef __attribute__((ext_vector_type(4))) float v4f;

#define M_TOK 16384        // 8 * 2048 tokens
#define DDIM 512
#define NCODES 8192
#define NTILE 64           // NCODES / 128
#define KCH 8              // 512 / 64 k-chunks

// workspace layout (bytes)
#define OFF_AH   0u            // 16 MB  f16(x)
#define OFF_BH   16777216u     //  8 MB  f16(cb)
#define OFF_PART 25165824u     //  8 MB  u64 per (token, ntile)
#define OFF_IDX  33554432u     // 64 KB
#define OFF_C2   33619968u     // 32 KB
#define OFF_ACC  33652736u     //  4 B

// ---------------- c2[k] = ||codebook[k]||^2 ----------------
__global__ void c2_kernel(const float* __restrict__ cb, float* __restrict__ c2) {
    int row  = blockIdx.x * 4 + (threadIdx.x >> 6);
    int lane = threadIdx.x & 63;
    const float* p = cb + (size_t)row * DDIM;
    float s = 0.f;
    #pragma unroll
    for (int d = 0; d < DDIM; d += 64) {
        float v = p[d + lane];
        s += v * v;
    }
    #pragma unroll
    for (int off = 32; off; off >>= 1) s += __shfl_down(s, off);
    if (lane == 0) c2[row] = s;
}

__global__ void zero_kernel(float* __restrict__ acc) {
    if (threadIdx.x == 0 && blockIdx.x == 0) *acc = 0.f;
}

// ---------------- fp32 -> f16, 8 elems/thread ----------------
__global__ void split_hi_kernel(const float* __restrict__ src, ushort_t* __restrict__ hi, int n8) {
    int i = blockIdx.x * blockDim.x + threadIdx.x;
    if (i >= n8) return;
    const float4* s4 = (const float4*)src + (size_t)i * 2;
    float4 a = s4[0], b = s4[1];
    float v[8] = {a.x, a.y, a.z, a.w, b.x, b.y, b.z, b.w};
    union { ushort_t u[8]; uint4 q; } H;
    #pragma unroll
    for (int j = 0; j < 8; ++j) {
        f16 h = (f16)v[j];
        __builtin_memcpy(&H.u[j], &h, 2);
    }
    *(uint4*)(hi + (size_t)i * 8) = H.q;
}

// ---------------- MFMA f16 GEMM, dbuf + counted vmcnt, per-block top-1 -----
// S[m][n] = f16(x[m]).f16(c[n]); score = c2[n] - 2 S.  Block: 128x128, 4 waves.
__launch_bounds__(256)
__global__ void gemm_top1_kernel(const ushort_t* __restrict__ Ah, const ushort_t* __restrict__ Bh,
                                 const float* __restrict__ c2, u64* __restrict__ part) {
    __shared__ __align__(16) ushort_t Asb[2][128 * 64];   // 2 x 16 KB
    __shared__ __align__(16) ushort_t Bsb[2][128 * 64];   // 2 x 16 KB
    __shared__ u64 mergebuf[128][2];

    const int tid = threadIdx.x;
    const int wid = tid >> 6;
    const int l   = tid & 63;
    const int wr  = wid >> 1, wc = wid & 1;
    const int mtile = blockIdx.x >> 6;      // 0..127
    const int ntile = blockIdx.x & 63;      // 0..63
    const int row0 = mtile * 128;
    const int col0 = ntile * 128;

    const int lg = l >> 4;                  // lane group 0..3
    const int lc = l & 15;

    // staging geometry (identical to verified round-3/4 kernels)
    const int srow  = l >> 3;               // row within 8-row group
    const int sslot = (l & 7) ^ srow;       // pre-swizzled source slot (G21)

    // 8 global_load_lds per thread per STAGE (4 A + 4 B) -> vmcnt counts below
    auto STAGE = [&](int buf, int kc) {
        const int k0 = kc * 64;
        #pragma unroll
        for (int i = 0; i < 4; ++i) {
            int rr = (wid * 4 + i) * 8 + srow;
            const ushort_t* ga = Ah + (size_t)(row0 + rr) * DDIM + k0 + sslot * 8;
            __builtin_amdgcn_global_load_lds(
                (const __attribute__((address_space(1))) void*)ga,
                (__attribute__((address_space(3))) void*)&Asb[buf][(wid * 4 + i) * 512], 16, 0, 0);
            const ushort_t* gb = Bh + (size_t)(col0 + rr) * DDIM + k0 + sslot * 8;
            __builtin_amdgcn_global_load_lds(
                (const __attribute__((address_space(1))) void*)gb,
                (__attribute__((address_space(3))) void*)&Bsb[buf][(wid * 4 + i) * 512], 16, 0, 0);
        }
    };

    v4f acc[4][4];
    #pragma unroll
    for (int m = 0; m < 4; ++m)
        #pragma unroll
        for (int n = 0; n < 4; ++n) acc[m][n] = (v4f){0.f, 0.f, 0.f, 0.f};

    STAGE(0, 0);
    int cur = 0;
    for (int kc = 0; kc < KCH; ++kc) {
        // B1: all waves done reading buf[cur^1] (targets of next STAGE)
        asm volatile("s_barrier" ::: "memory");
        if (kc < KCH - 1) {
            STAGE(cur ^ 1, kc + 1);
            // wait only for the PREVIOUS stage (8 oldest of <=16 outstanding);
            // the 8 just-issued loads stay in flight through compute.
            asm volatile("s_waitcnt vmcnt(8)" ::: "memory");
        } else {
            asm volatile("s_waitcnt vmcnt(0)" ::: "memory");
        }
        // B2: every wave has passed its vmcnt -> stage(kc) visible to all
        asm volatile("s_barrier" ::: "memory");

        #pragma unroll
        for (int ks = 0; ks < 2; ++ks) {
            v8h af[4], bf[4];
            #pragma unroll
            for (int m = 0; m < 4; ++m) {
                int row = wr * 64 + m * 16 + lc;
                int slot = ks * 4 + lg;
                int byteoff = row * 128 + ((slot ^ (row & 7)) * 16);
                af[m] = *(const v8h*)((const char*)&Asb[cur][0] + byteoff);
            }
            #pragma unroll
            for (int n = 0; n < 4; ++n) {
                int row = wc * 64 + n * 16 + lc;
                int slot = ks * 4 + lg;
                int byteoff = row * 128 + ((slot ^ (row & 7)) * 16);
                bf[n] = *(const v8h*)((const char*)&Bsb[cur][0] + byteoff);
            }
            #pragma unroll
            for (int m = 0; m < 4; ++m)
                #pragma unroll
                for (int n = 0; n < 4; ++n)
                    acc[m][n] = __builtin_amdgcn_mfma_f32_16x16x32_f16(af[m], bf[n], acc[m][n], 0, 0, 0);
        }
        cur ^= 1;
    }

    // ---- epilogue: per-row min over this block's 128 columns, packed u64 ----
    // D layout: col = lc, row = lg*4 + j (verified rounds 3/4)
    float c2v[4];
    #pragma unroll
    for (int n = 0; n < 4; ++n) c2v[n] = c2[col0 + wc * 64 + n * 16 + lc];

    #pragma unroll
    for (int m = 0; m < 4; ++m) {
        #pragma unroll
        for (int j = 0; j < 4; ++j) {
            int rloc = wr * 64 + m * 16 + lg * 4 + j;
            u64 best = ~0ull;
            #pragma unroll
            for (int n = 0; n < 4; ++n) {
                float s = c2v[n] - 2.0f * acc[m][n][j];
                u32 b = __float_as_uint(s);
                b = (b & 0x80000000u) ? ~b : (b | 0x80000000u);   // monotone float->u32
                int col = col0 + wc * 64 + n * 16 + lc;
                u64 key = ((u64)b << 32) | (u32)col;              // low bits: index tie-break
                best = key < best ? key : best;
            }
            #pragma unroll
            for (int off = 1; off < 16; off <<= 1) {
                u64 o = __shfl_xor(best, off);
                best = o < best ? o : best;
            }
            if (lc == 0) mergebuf[rloc][wc] = best;
        }
    }
    __syncthreads();
    if (tid < 128) {
        u64 a = mergebuf[tid][0], b = mergebuf[tid][1];
        part[(size_t)(row0 + tid) * NTILE + ntile] = a < b ? a : b;
    }
}

// ---------------- merge 64 block winners -> top-4 + exact fp64 recheck ----
__global__ void reduce_recheck_kernel(const u64* __restrict__ part,
                                      const float* __restrict__ x, const float* __restrict__ cb,
                                      int* __restrict__ idx) {
    int t = blockIdx.x * 4 + (threadIdx.x >> 6);
    int l = threadIdx.x & 63;
    u64 k = part[(size_t)t * NTILE + l];

    int cand[4];
    #pragma unroll
    for (int c = 0; c < 4; ++c) {
        u64 m = k;
        #pragma unroll
        for (int off = 1; off < 64; off <<= 1) {
            u64 o = __shfl_xor(m, off);
            m = o < m ? o : m;
        }
        cand[c] = (int)(u32)(m & 0xffffffffull);
        if (k == m) k = ~0ull;        // keys unique (distinct cols) -> removes one lane
    }

    const float* xp = x + (size_t)t * DDIM + l * 8;
    float xv[8];
    #pragma unroll
    for (int j = 0; j < 8; ++j) xv[j] = xp[j];

    double d[4];
    #pragma unroll
    for (int c = 0; c < 4; ++c) {
        const float* cp = cb + (size_t)cand[c] * DDIM + l * 8;
        double s = 0.0;
        #pragma unroll
        for (int j = 0; j < 8; ++j) {
            double a = (double)cp[j] - (double)xv[j];
            s += a * a;
        }
        d[c] = s;
    }
    #pragma unroll
    for (int c = 0; c < 4; ++c) {
        #pragma unroll
        for (int off = 1; off < 64; off <<= 1) d[c] += __shfl_xor(d[c], off);
    }

    double bd = d[0]; int bi = cand[0];
    #pragma unroll
    for (int c = 1; c < 4; ++c)
        if (d[c] < bd || (d[c] == bd && cand[c] < bi)) { bd = d[c]; bi = cand[c]; }
    if (l == 0) idx[t] = bi;
}

// ---------------- gather codes, straight-through output, loss (float4) ----
__global__ void quantize_kernel(const float* __restrict__ x, const float* __restrict__ cb,
                                const int* __restrict__ idx, float* __restrict__ out,
                                float* __restrict__ acc) {
    __shared__ float red[4];
    float local = 0.f;
    const int nvec = M_TOK * DDIM / 4;    // 2,097,152 float4
    for (int v = blockIdx.x * blockDim.x + threadIdx.x; v < nvec;
         v += gridDim.x * blockDim.x) {
        int t  = v >> 7;                  // 128 float4 per token
        int d4 = (v & 127) * 4;
        int k = idx[t];
        float4 c  = *(const float4*)(cb + (size_t)k * DDIM + d4);
        float4 xv = *(const float4*)(x + (size_t)v * 4);
        float dx = c.x - xv.x, dy = c.y - xv.y, dz = c.z - xv.z, dw = c.w - xv.w;
        float4 o;
        o.x = xv.x + dx; o.y = xv.y + dy; o.z = xv.z + dz; o.w = xv.w + dw;
        *(float4*)(out + (size_t)v * 4) = o;
        local += dx * dx + dy * dy + dz * dz + dw * dw;
    }
    #pragma unroll
    for (int off = 32; off; off >>= 1) local += __shfl_down(local, off);
    int lane = threadIdx.x & 63, wv = threadIdx.x >> 6;
    if (lane == 0) red[wv] = local;
    __syncthreads();
    if (threadIdx.x == 0) atomicAdd(acc, red[0] + red[1] + red[2] + red[3]);
}

__global__ void finalize_kernel(const int* __restrict__ idx, const float* __restrict__ acc,
                                float* __restrict__ out) {
    int t = blockIdx.x * blockDim.x + threadIdx.x;
    if (t < M_TOK) out[(size_t)M_TOK * DDIM + t] = (float)idx[t];
    if (t == 0) {
        float mean = (*acc) / (float)((size_t)M_TOK * DDIM);
        out[(size_t)M_TOK * DDIM + M_TOK] = 2.0f * mean;
    }
}

extern "C" void kernel_launch(void* const* d_in, const int* in_sizes, int n_in,
                              void* d_out, int out_size, void* d_ws, size_t ws_size,
                              hipStream_t stream) {
    const float* x  = (const float*)d_in[0];
    const float* cb = (const float*)d_in[1];
    float* out = (float*)d_out;
    char* ws = (char*)d_ws;

    ushort_t* Ah   = (ushort_t*)(ws + OFF_AH);
    ushort_t* Bh   = (ushort_t*)(ws + OFF_BH);
    u64*      part = (u64*)(ws + OFF_PART);
    int*      idx  = (int*)(ws + OFF_IDX);
    float*    c2   = (float*)(ws + OFF_C2);
    float*    acc  = (float*)(ws + OFF_ACC);

    zero_kernel<<<1, 64, 0, stream>>>(acc);
    c2_kernel<<<NCODES / 4, 256, 0, stream>>>(cb, c2);
    split_hi_kernel<<<(M_TOK * DDIM / 8) / 256, 256, 0, stream>>>(x, Ah, M_TOK * DDIM / 8);
    split_hi_kernel<<<(NCODES * DDIM / 8) / 256, 256, 0, stream>>>(cb, Bh, NCODES * DDIM / 8);
    gemm_top1_kernel<<<(M_TOK / 128) * NTILE, 256, 0, stream>>>(Ah, Bh, c2, part);
    reduce_recheck_kernel<<<M_TOK / 4, 256, 0, stream>>>(part, x, cb, idx);
    quantize_kernel<<<2048, 256, 0, stream>>>(x, cb, idx, out, acc);
    finalize_kernel<<<(M_TOK + 255) / 256, 256, 0, stream>>>(idx, acc, out);
}

// Round 8
// 270.190 us; speedup vs baseline: 1.4738x; 1.0535x over previous
//
#include <hip/hip_runtime.h>
#include <hip/hip_bf16.h>

typedef unsigned short ushort_t;
typedef unsigned int u32;
typedef unsigned long long u64;
typedef _Float16 f16;
typedef __attribute__((ext_vector_type(8))) _Float16 v8h;
typedef __attribute__((ext_vector_type(4))) float v4f;

#define M_TOK 16384        // 8 * 2048 tokens
#define DDIM 512
#define NCODES 8192
#define NTILE 64           // NCODES / 128
#define BK 32
#define KCH 16             // 512 / BK

// workspace layout (bytes)
#define OFF_AH   0u            // 16 MB  f16(x)
#define OFF_BH   16777216u     //  8 MB  f16(cb)
#define OFF_PART 25165824u     //  8 MB  u64 per (token, ntile)
#define OFF_C2   33554432u     // 32 KB
#define OFF_ACC  33587200u     //  4 B

__global__ void zero_kernel(float* __restrict__ acc) {
    if (threadIdx.x == 0 && blockIdx.x == 0) *acc = 0.f;
}

// ---------------- cb: fp32 -> f16 + c2 in one pass (1 row per wave) -------
__global__ void split_cb_c2_kernel(const float* __restrict__ cb, ushort_t* __restrict__ Bh,
                                   float* __restrict__ c2) {
    int row  = blockIdx.x * 4 + (threadIdx.x >> 6);
    int l    = threadIdx.x & 63;
    const float* p = cb + (size_t)row * DDIM + l * 8;
    float4 a = *(const float4*)p;
    float4 b = *(const float4*)(p + 4);
    float v[8] = {a.x, a.y, a.z, a.w, b.x, b.y, b.z, b.w};
    union { ushort_t u[8]; uint4 q; } H;
    float s = 0.f;
    #pragma unroll
    for (int j = 0; j < 8; ++j) {
        f16 h = (f16)v[j];
        __builtin_memcpy(&H.u[j], &h, 2);
        s += v[j] * v[j];
    }
    *(uint4*)(Bh + (size_t)row * DDIM + l * 8) = H.q;
    #pragma unroll
    for (int off = 32; off; off >>= 1) s += __shfl_down(s, off);
    if (l == 0) c2[row] = s;
}

// ---------------- x: fp32 -> f16, 8 elems/thread ----------------
__global__ void split_hi_kernel(const float* __restrict__ src, ushort_t* __restrict__ hi, int n8) {
    int i = blockIdx.x * blockDim.x + threadIdx.x;
    if (i >= n8) return;
    const float4* s4 = (const float4*)src + (size_t)i * 2;
    float4 a = s4[0], b = s4[1];
    float v[8] = {a.x, a.y, a.z, a.w, b.x, b.y, b.z, b.w};
    union { ushort_t u[8]; uint4 q; } H;
    #pragma unroll
    for (int j = 0; j < 8; ++j) {
        f16 h = (f16)v[j];
        __builtin_memcpy(&H.u[j], &h, 2);
    }
    *(uint4*)(hi + (size_t)i * 8) = H.q;
}

// ---------------- MFMA f16 GEMM, BK=32 dbuf + counted vmcnt, top-1 --------
// S[m][n] = f16(x[m]).f16(c[n]); score = c2[n] - 2 S.  Block: 128x128, 4 waves.
// LDS: 2 x (8KB A + 8KB B) + 2KB merge = 34 KB -> 4 blocks/CU.
__launch_bounds__(256, 4)
__global__ void gemm_top1_kernel(const ushort_t* __restrict__ Ah, const ushort_t* __restrict__ Bh,
                                 const float* __restrict__ c2, u64* __restrict__ part) {
    __shared__ __align__(16) ushort_t Asb[2][128 * BK];   // 2 x 8 KB
    __shared__ __align__(16) ushort_t Bsb[2][128 * BK];   // 2 x 8 KB
    __shared__ u64 mergebuf[128][2];

    const int tid = threadIdx.x;
    const int wid = tid >> 6;
    const int l   = tid & 63;
    const int wr  = wid >> 1, wc = wid & 1;
    const int mtile = blockIdx.x >> 6;      // 0..127
    const int ntile = blockIdx.x & 63;      // 0..63
    const int row0 = mtile * 128;
    const int col0 = ntile * 128;

    const int lg = l >> 4;                  // lane group 0..3
    const int lc = l & 15;

    // staging: per gld, 16 rows x 64B; lane l -> row (l>>2), dest slot (l&3).
    // LDS[row][s] holds global k-slot s ^ ((row>>1)&3)  (2-way banks on read).
    const int srowoff = l >> 2;
    const int sslot   = (l & 3) ^ ((l >> 3) & 3);   // pre-swizzled source slot

    // 4 global_load_lds per thread per STAGE (2 A + 2 B)
    auto STAGE = [&](int buf, int kc) {
        const int k0 = kc * BK;
        #pragma unroll
        for (int i = 0; i < 2; ++i) {
            int rbase = i * 64 + wid * 16;
            int row = rbase + srowoff;
            const ushort_t* ga = Ah + (size_t)(row0 + row) * DDIM + k0 + sslot * 8;
            __builtin_amdgcn_global_load_lds(
                (const __attribute__((address_space(1))) void*)ga,
                (__attribute__((address_space(3))) void*)&Asb[buf][rbase * BK], 16, 0, 0);
            const ushort_t* gb = Bh + (size_t)(col0 + row) * DDIM + k0 + sslot * 8;
            __builtin_amdgcn_global_load_lds(
                (const __attribute__((address_space(1))) void*)gb,
                (__attribute__((address_space(3))) void*)&Bsb[buf][rbase * BK], 16, 0, 0);
        }
    };

    v4f acc[4][4];
    #pragma unroll
    for (int m = 0; m < 4; ++m)
        #pragma unroll
        for (int n = 0; n < 4; ++n) acc[m][n] = (v4f){0.f, 0.f, 0.f, 0.f};

    STAGE(0, 0);
    int cur = 0;
    const int slotbyte = (lg ^ ((lc >> 1) & 3)) * 16;   // read swizzle (round-trips to k-slot lg)
    for (int kc = 0; kc < KCH; ++kc) {
        // RACE FIX: our ds_reads of buf[cur^1] (prev iter) must COMPLETE before
        // we release B1 (which authorizes other waves to overwrite that buffer).
        // A raw s_barrier does not drain lgkmcnt; __syncthreads would (round 4).
        asm volatile("s_waitcnt lgkmcnt(0)" ::: "memory");
        __builtin_amdgcn_sched_barrier(0);
        // B1: all waves done reading buf[cur^1] (target of next STAGE)
        asm volatile("s_barrier" ::: "memory");
        if (kc < KCH - 1) {
            STAGE(cur ^ 1, kc + 1);
            // wait only for the PREVIOUS stage (4 oldest); new 4 stay in flight
            asm volatile("s_waitcnt vmcnt(4)" ::: "memory");
        } else {
            asm volatile("s_waitcnt vmcnt(0)" ::: "memory");
        }
        // B2: every wave passed its vmcnt -> stage(kc) visible to all
        asm volatile("s_barrier" ::: "memory");

        v8h af[4], bf[4];
        #pragma unroll
        for (int m = 0; m < 4; ++m) {
            int row = wr * 64 + m * 16 + lc;
            af[m] = *(const v8h*)((const char*)&Asb[cur][0] + row * 64 + slotbyte);
        }
        #pragma unroll
        for (int n = 0; n < 4; ++n) {
            int row = wc * 64 + n * 16 + lc;
            bf[n] = *(const v8h*)((const char*)&Bsb[cur][0] + row * 64 + slotbyte);
        }
        #pragma unroll
        for (int m = 0; m < 4; ++m)
            #pragma unroll
            for (int n = 0; n < 4; ++n)
                acc[m][n] = __builtin_amdgcn_mfma_f32_16x16x32_f16(af[m], bf[n], acc[m][n], 0, 0, 0);
        cur ^= 1;
    }

    // ---- epilogue: per-row min over this block's 128 columns, packed u64 ----
    // D layout: col = lc, row = lg*4 + j (verified rounds 3/4/6)
    float c2v[4];
    #pragma unroll
    for (int n = 0; n < 4; ++n) c2v[n] = c2[col0 + wc * 64 + n * 16 + lc];

    #pragma unroll
    for (int m = 0; m < 4; ++m) {
        #pragma unroll
        for (int j = 0; j < 4; ++j) {
            int rloc = wr * 64 + m * 16 + lg * 4 + j;
            u64 best = ~0ull;
            #pragma unroll
            for (int n = 0; n < 4; ++n) {
                float s = c2v[n] - 2.0f * acc[m][n][j];
                u32 b = __float_as_uint(s);
                b = (b & 0x80000000u) ? ~b : (b | 0x80000000u);   // monotone float->u32
                int col = col0 + wc * 64 + n * 16 + lc;
                u64 key = ((u64)b << 32) | (u32)col;              // low bits: index tie-break
                best = key < best ? key : best;
            }
            #pragma unroll
            for (int off = 1; off < 16; off <<= 1) {
                u64 o = __shfl_xor(best, off);
                best = o < best ? o : best;
            }
            if (lc == 0) mergebuf[rloc][wc] = best;
        }
    }
    __syncthreads();   // full drain (vmcnt+lgkmcnt) before cross-wave merge read
    if (tid < 128) {
        u64 a = mergebuf[tid][0], b = mergebuf[tid][1];
        part[(size_t)(row0 + tid) * NTILE + ntile] = a < b ? a : b;
    }
}

// ---- merge 64 winners -> top-4, fp64 recheck, quantize + idx + loss ------
__global__ void reduce_quant_kernel(const u64* __restrict__ part,
                                    const float* __restrict__ x, const float* __restrict__ cb,
                                    float* __restrict__ out, float* __restrict__ acc) {
    __shared__ float red[4];
    int t = blockIdx.x * 4 + (threadIdx.x >> 6);
    int l = threadIdx.x & 63;
    u64 k = part[(size_t)t * NTILE + l];

    int cand[4];
    #pragma unroll
    for (int c = 0; c < 4; ++c) {
        u64 m = k;
        #pragma unroll
        for (int off = 1; off < 64; off <<= 1) {
            u64 o = __shfl_xor(m, off);
            m = o < m ? o : m;
        }
        cand[c] = (int)(u32)(m & 0xffffffffull);
        if (k == m) k = ~0ull;        // keys unique (distinct cols) -> removes one lane
    }

    const float* xp = x + (size_t)t * DDIM + l * 8;
    float xv[8];
    #pragma unroll
    for (int j = 0; j < 8; ++j) xv[j] = xp[j];

    float cp[4][8];
    double d[4];
    #pragma unroll
    for (int c = 0; c < 4; ++c) {
        const float* cpp = cb + (size_t)cand[c] * DDIM + l * 8;
        double s = 0.0;
        #pragma unroll
        for (int j = 0; j < 8; ++j) {
            cp[c][j] = cpp[j];
            double a = (double)cp[c][j] - (double)xv[j];
            s += a * a;
        }
        d[c] = s;
    }
    #pragma unroll
    for (int c = 0; c < 4; ++c) {
        #pragma unroll
        for (int off = 1; off < 64; off <<= 1) d[c] += __shfl_xor(d[c], off);
    }

    double bd = d[0]; int bi = cand[0]; int bc = 0;
    #pragma unroll
    for (int c = 1; c < 4; ++c)
        if (d[c] < bd || (d[c] == bd && cand[c] < bi)) { bd = d[c]; bi = cand[c]; bc = c; }

    // winning code row (compile-time-indexed select, rule #20)
    float cw[8];
    #pragma unroll
    for (int j = 0; j < 8; ++j) {
        float v = cp[0][j];
        #pragma unroll
        for (int c = 1; c < 4; ++c) v = (bc == c) ? cp[c][j] : v;
        cw[j] = v;
    }

    // quantized out = x + (codes - x); loss partial = sum diff^2
    float ls = 0.f;
    float4 o0, o1;
    float dj[8];
    #pragma unroll
    for (int j = 0; j < 8; ++j) { dj[j] = cw[j] - xv[j]; ls += dj[j] * dj[j]; }
    o0.x = xv[0] + dj[0]; o0.y = xv[1] + dj[1]; o0.z = xv[2] + dj[2]; o0.w = xv[3] + dj[3];
    o1.x = xv[4] + dj[4]; o1.y = xv[5] + dj[5]; o1.z = xv[6] + dj[6]; o1.w = xv[7] + dj[7];
    float* op = out + (size_t)t * DDIM + l * 8;
    *(float4*)op = o0;
    *(float4*)(op + 4) = o1;

    if (l == 0) out[(size_t)M_TOK * DDIM + t] = (float)bi;   // index as fp32

    #pragma unroll
    for (int off = 32; off; off >>= 1) ls += __shfl_down(ls, off);
    int wv = threadIdx.x >> 6;
    if (l == 0) red[wv] = ls;
    __syncthreads();
    if (threadIdx.x == 0) atomicAdd(acc, red[0] + red[1] + red[2] + red[3]);
}

__global__ void loss_final_kernel(const float* __restrict__ acc, float* __restrict__ out) {
    if (threadIdx.x == 0 && blockIdx.x == 0) {
        float mean = (*acc) / (float)((size_t)M_TOK * DDIM);
        out[(size_t)M_TOK * DDIM + M_TOK] = 2.0f * mean;
    }
}

extern "C" void kernel_launch(void* const* d_in, const int* in_sizes, int n_in,
                              void* d_out, int out_size, void* d_ws, size_t ws_size,
                              hipStream_t stream) {
    const float* x  = (const float*)d_in[0];
    const float* cb = (const float*)d_in[1];
    float* out = (float*)d_out;
    char* ws = (char*)d_ws;

    ushort_t* Ah   = (ushort_t*)(ws + OFF_AH);
    ushort_t* Bh   = (ushort_t*)(ws + OFF_BH);
    u64*      part = (u64*)(ws + OFF_PART);
    float*    c2   = (float*)(ws + OFF_C2);
    float*    acc  = (float*)(ws + OFF_ACC);

    zero_kernel<<<1, 64, 0, stream>>>(acc);
    split_cb_c2_kernel<<<NCODES / 4, 256, 0, stream>>>(cb, Bh, c2);
    split_hi_kernel<<<(M_TOK * DDIM / 8) / 256, 256, 0, stream>>>(x, Ah, M_TOK * DDIM / 8);
    gemm_top1_kernel<<<(M_TOK / 128) * NTILE, 256, 0, stream>>>(Ah, Bh, c2, part);
    reduce_quant_kernel<<<M_TOK / 4, 256, 0, stream>>>(part, x, cb, out, acc);
    loss_final_kernel<<<1, 64, 0, stream>>>(acc, out);
}